// Round 16
// baseline (278.034 us; speedup 1.0000x reference)
//
#include <hip/hip_runtime.h>
#include <hip/hip_bf16.h>
#include <math.h>

#define CH 128
#define IMGW 256
#define NIMG 10
#define HW 65536
#define FEATS_ELEMS ((size_t)NIMG*CH*HW)

typedef __attribute__((ext_vector_type(8))) short short8;
typedef __attribute__((ext_vector_type(4))) float f32x4;

// workspace layout (float offsets) — R8 layout
#define WS_W1BF 0          // W1 bf16 [128 o][128 c]
#define WS_W2BF 8192
#define WS_PART 16384      // [5120 logical strips][16] stat partials
#define WS_A    98304      // [10][128] rsig*gn_w
#define WS_CC   99584      // [10][128] affine constant
#define WS_LOSS 100864     // [5120*8] per-(strip,wave) loss partials
#define WS_HT   141824     // h cache: 5120 strips * 8192 floats (16384 bf16)

static __device__ __forceinline__ ushort f2bf(float f) {
    __hip_bfloat16 h = __float2bfloat16(f);
    return *reinterpret_cast<ushort*>(&h);
}
static __device__ __forceinline__ uint pack2(float a, float b) {
    return (uint)f2bf(a) | ((uint)f2bf(b) << 16);
}
static __device__ __forceinline__ float gelu_fast(float v) {
    float v2 = v*v;
    float z2 = v * fmaf(0.07135481627f, v2, 1.59576912161f);
    return v / (1.0f + __expf(-z2));
}
// 4x4 cross-lane transpose among lanes differing in masks m1 (role bit1)
// and m0 (role bit0); a = role index 0..3.
static __device__ __forceinline__ void xpose4m(int a, int m1, int m0,
        float& r0, float& r1, float& r2, float& r3) {
    float s0v = (a&2) ? r0 : r2, s1v = (a&2) ? r1 : r3;
    float u0 = __shfl_xor(s0v, m1), u1 = __shfl_xor(s1v, m1);
    if (a&2) { r0 = u0; r1 = u1; } else { r2 = u0; r3 = u1; }
    float sA = (a&1) ? r0 : r1; float uA = __shfl_xor(sA, m0);
    if (a&1) r0 = uA; else r1 = uA;
    float sB = (a&1) ? r2 : r3; float uB = __shfl_xor(sB, m0);
    if (a&1) r2 = uB; else r3 = uB;
}

// ------------------------------------------------ K0: W->bf16
__global__ void k0_init(const float* __restrict__ W1, const float* __restrict__ W2,
                        float* __restrict__ ws) {
    int idx = blockIdx.x*256 + threadIdx.x;     // 0..16383
    uint* w1b = (uint*)(ws + WS_W1BF);
    uint* w2b = (uint*)(ws + WS_W2BF);
    if (idx < 8192) {
        w1b[idx] = pack2(W1[2*idx], W1[2*idx+1]);
    } else {
        int j = idx - 8192;
        w2b[j] = pack2(W2[2*j], W2[2*j+1]);
    }
}

// K1: QUAD-STRIP (8 rows x 32 cols = 4 windows = 2 h-strips), 512 thr.
// Full 128B-line NT wave-loads; sched_barrier(0) pins all 16 loads ABOVE the
// pack loop so they are issued together and drained with progressive vmcnt —
// R11's VGPR=44 proved the compiler otherwise sinks each load to its use,
// serializing 16 x ~900cy NT latency per wave.
__global__ __launch_bounds__(512, 4) void k1_quad(const float* __restrict__ x,
        float* ws, const float* __restrict__ b1v) {
    __shared__ __align__(16) ushort xq[256*128];   // x^T then h^T (64 KB)
    __shared__ float sp[32];
    const int t = threadIdx.x, b = blockIdx.x;
    const int qidx = (b & 7)*320 + (b >> 3);       // bijective, 2560%8==0
    const int n = qidx >> 8, rem = qidx & 255;
    const int sr = rem >> 3, qc = rem & 7;
    const int h0 = sr*8, w0q = qc*32;
    const size_t g0 = (size_t)n*512 + sr*16 + 2*qc;   // logical strip ids
    const int l = t & 63, wid = t >> 6;
    const int lm = l & 15, lg = l >> 4;
    const int swzl = 8*(lm&7);
    const ushort* w1b = (const ushort*)(ws + WS_W1BF);
    const int ow = wid & 3, o0 = 32*ow;

    // ---- staging: 16 NT wave-loads, each = 8 full 128B lines
    const int oct = l >> 3, j = l & 7;
    f32x4 v[16];
    {
        const float* xb = x + (size_t)n*CH*HW + (size_t)h0*IMGW + w0q;
        #pragma unroll
        for (int i = 0; i < 16; ++i) {
            int c = (i & 1)*64 + 8*wid + oct;
            int dy = i >> 1;
            v[i] = __builtin_nontemporal_load(
                       (const f32x4*)(xb + (size_t)c*HW + dy*IMGW + 4*j));
        }
    }
    // Pin: nothing below may be hoisted above; the 16 loads may not sink.
    __builtin_amdgcn_sched_barrier(0);

    short8 af[2][4];
    #pragma unroll
    for (int ot = 0; ot < 2; ++ot)
        #pragma unroll
        for (int ks = 0; ks < 4; ++ks)
            af[ot][ks] = *(const short8*)(w1b + (size_t)(o0 + ot*16 + lm)*128 + ks*32 + 8*lg);
    float bv[2][4];
    #pragma unroll
    for (int ot = 0; ot < 2; ++ot)
        #pragma unroll
        for (int r = 0; r < 4; ++r) bv[ot][r] = b1v[o0 + ot*16 + 4*lg + r];

    // ---- transpose (4x4 across lane-xor 16/8) + pack -> xq[P][c^swz]
    {
        const int a = oct & 3, A = oct >> 2;
        #pragma unroll
        for (int i = 0; i < 16; ++i) {
            float r0 = v[i][0], r1 = v[i][1], r2 = v[i][2], r3 = v[i][3];
            xpose4m(a, 16, 8, r0, r1, r2, r3);
            int col = 4*j + a;                       // 0..31 within quad
            int P = (col >> 3)*64 + (i >> 1)*8 + (col & 7);
            int cq = (i & 1)*64 + 8*wid + 4*A;
            uint2 pk; pk.x = pack2(r0, r1); pk.y = pack2(r2, r3);
            *(uint2*)&xq[P*128 + (cq ^ (8*(P&7)))] = pk;
        }
    }
    __syncthreads();

    // ---- conv1 in 2 phases (phase ph: windows 2ph + (wid>>2))
    float s1[2] = {0.f, 0.f}, s2[2] = {0.f, 0.f};
    #pragma unroll
    for (int ph = 0; ph < 2; ++ph) {
        const int win = 2*ph + (wid >> 2);
        f32x4 hacc[2][4];
        #pragma unroll
        for (int ot = 0; ot < 2; ++ot)
            #pragma unroll
            for (int pt = 0; pt < 4; ++pt)
                hacc[ot][pt] = (f32x4){bv[ot][0], bv[ot][1], bv[ot][2], bv[ot][3]};
        #pragma unroll
        for (int ks = 0; ks < 4; ++ks)
            #pragma unroll
            for (int pt = 0; pt < 4; ++pt) {
                short8 bfr = *(const short8*)&xq[(win*64 + pt*16 + lm)*128 + ((ks*32 + 8*lg) ^ swzl)];
                hacc[0][pt] = __builtin_amdgcn_mfma_f32_16x16x32_bf16(af[0][ks], bfr, hacc[0][pt], 0,0,0);
                hacc[1][pt] = __builtin_amdgcn_mfma_f32_16x16x32_bf16(af[1][ks], bfr, hacc[1][pt], 0,0,0);
            }
        #pragma unroll
        for (int ot = 0; ot < 2; ++ot)
            #pragma unroll
            for (int pt = 0; pt < 4; ++pt)
                #pragma unroll
                for (int r = 0; r < 4; ++r) {
                    float h = hacc[ot][pt][r];
                    s1[ot] += h; s2[ot] += h*h;
                }
        __syncthreads();   // all reads of this phase's windows complete
        // h^T write in place (rows of this phase only)
        #pragma unroll
        for (int ot = 0; ot < 2; ++ot)
            #pragma unroll
            for (int pt = 0; pt < 4; ++pt) {
                f32x4 h = hacc[ot][pt];
                int P = win*64 + pt*16 + lm;
                uint2 pk; pk.x = pack2(h[0], h[1]); pk.y = pack2(h[2], h[3]);
                *(uint2*)&xq[P*128 + ((o0 + ot*16 + 4*lg) ^ swzl)] = pk;
            }
        // phase B conv reads rows 128..255 — disjoint from phase A h-writes
    }

    // ---- stats: wave-reduce, stash per wave
    #pragma unroll
    for (int ot = 0; ot < 2; ++ot) {
        float a = s1[ot], qq = s2[ot];
        #pragma unroll
        for (int off = 1; off < 64; off <<= 1) {
            a += __shfl_xor(a, off); qq += __shfl_xor(qq, off);
        }
        if (l == 0) { sp[wid*4 + ot*2] = a; sp[wid*4 + ot*2 + 1] = qq; }
    }
    __syncthreads();   // h^T complete (both phases) + sp ready

    // ---- stream LDS -> both h-cache strips (verbatim, contiguous)
    {
        const uint4* srcv = (const uint4*)xq;
        uint4* d0 = (uint4*)(ws + WS_HT + g0*8192);
        uint4* d1 = (uint4*)(ws + WS_HT + (g0+1)*8192);
        #pragma unroll
        for (int i = 0; i < 4; ++i) d0[t + i*512] = srcv[t + i*512];
        #pragma unroll
        for (int i = 0; i < 4; ++i) d1[t + i*512] = srcv[2048 + t + i*512];
    }

    // ---- stat partials: combined into strip g0's slots; zeros into g1's
    if (t < 16) {
        int which = t >> 3, g = t & 7;
        int ow_ = g >> 1, ot_ = g & 1;
        float vv = sp[ow_*4 + ot_*2 + which] + sp[(4+ow_)*4 + ot_*2 + which];
        ws[WS_PART + g0*16 + t] = vv;
        ws[WS_PART + (g0+1)*16 + t] = 0.0f;
    }
}

// K2: parallel reduce of strip partials (grid 10 = one block per image)
__global__ __launch_bounds__(256) void k2_final(const float* __restrict__ gnw,
        const float* __restrict__ gnb, float* ws) {
    __shared__ float red[256];
    __shared__ float tot[16];
    __shared__ float muS[8], rsS[8];
    const int t = threadIdx.x, n = blockIdx.x;
    const int s = t & 15, i0 = t >> 4;
    const float* base = ws + WS_PART + (size_t)n*512*16;
    float p = 0.f;
    for (int k = 0; k < 32; ++k) p += base[(i0 + 16*k)*16 + s];
    red[t] = p;
    __syncthreads();
    if (t < 16) {
        float v = 0.f;
        #pragma unroll
        for (int jj = 0; jj < 16; ++jj) v += red[jj*16 + t];
        tot[t] = v;
    }
    __syncthreads();
    if (t < 8) {
        const float inv = 1.0f/1048576.0f;      // 16 ch * 65536 px
        float mu  = tot[t]*inv;
        float var = tot[8 + t]*inv - mu*mu;
        muS[t] = mu; rsS[t] = rsqrtf(var + 1e-5f);
    }
    __syncthreads();
    if (t < 128) {
        int g = t >> 4;
        float a = rsS[g]*gnw[t];
        ws[WS_A  + n*128 + t] = a;
        ws[WS_CC + n*128 + t] = gnb[t] - muS[g]*a;   // b1 already inside h
    }
}

// K3 (== R8): 2-window strip, h via global_load_lds, GN+GELU in place,
// conv2, LDS-staged 64B NT feats stores, Gram + LSE.
__global__ __launch_bounds__(512, 4) void k3_consume(float* ws,
        const float* __restrict__ b2v, const float* __restrict__ temp,
        float* __restrict__ out) {
    __shared__ __align__(16) ushort fb[128*128];   // h -> g -> f^T bf16 (32 KB)
    __shared__ __align__(16) float  st[64*136];    // fp32 out staging  (34 KB)
    const int t = threadIdx.x, b = blockIdx.x;
    const int swz = (b & 7)*640 + (b >> 3);        // logical strip id
    const int n = swz >> 9, strip = swz & 511;
    const int h0 = (strip >> 4)*8, w0c = (strip & 15)*16;
    const int l = t & 63, wid = t >> 6;
    const int lm = l & 15, lg = l >> 4;
    const int swzl = 8*(lm&7);
    const ushort* w2b = (const ushort*)(ws + WS_W2BF);

    // ---- load h strip: direct global->LDS (verbatim; lane-linear both sides)
    {
        const char* src = (const char*)(ws + WS_HT + (size_t)swz*8192);
        #pragma unroll
        for (int i = 0; i < 4; ++i) {
            __builtin_amdgcn_global_load_lds(
                (const __attribute__((address_space(1))) void*)(src + ((size_t)(t + i*512))*16),
                (__attribute__((address_space(3))) void*)&fb[(size_t)(t + i*512)*8],
                16, 0, 0);
        }
    }
    __syncthreads();

    // ---- GN affine + GELU, in place (4096 uint2 / 512 thr)
    {
        uint2* hu = (uint2*)fb;
        const float* aP = ws + WS_A  + n*128;
        const float* cP = ws + WS_CC + n*128;
        #pragma unroll
        for (int i = 0; i < 8; ++i) {
            int c0 = t + i*512;
            int p = c0 >> 5;
            int o = ((c0 & 31)*4) ^ (8*(p&7));
            uint2 v = hu[c0];
            float hv0 = __uint_as_float((v.x & 0xffffu) << 16);
            float hv1 = __uint_as_float(v.x & 0xffff0000u);
            float hv2 = __uint_as_float((v.y & 0xffffu) << 16);
            float hv3 = __uint_as_float(v.y & 0xffff0000u);
            float g0 = gelu_fast(fmaf(hv0, aP[o],   cP[o]));
            float g1 = gelu_fast(fmaf(hv1, aP[o+1], cP[o+1]));
            float g2 = gelu_fast(fmaf(hv2, aP[o+2], cP[o+2]));
            float g3 = gelu_fast(fmaf(hv3, aP[o+3], cP[o+3]));
            uint2 pk; pk.x = pack2(g0, g1); pk.y = pack2(g2, g3);
            hu[c0] = pk;
        }
    }
    __syncthreads();

    const int win = wid >> 2, ow = wid & 3;
    const int o0 = 32*ow, pB = win*64;
    const int half = ow >> 1;                      // channel-half of this wave

    // ---- conv2
    short8 af2[2][4];
    #pragma unroll
    for (int ot = 0; ot < 2; ++ot)
        #pragma unroll
        for (int ks = 0; ks < 4; ++ks)
            af2[ot][ks] = *(const short8*)(w2b + (size_t)(o0 + ot*16 + lm)*128 + ks*32 + 8*lg);
    f32x4 facc[2][4];
    #pragma unroll
    for (int ot = 0; ot < 2; ++ot)
        #pragma unroll
        for (int pt = 0; pt < 4; ++pt) facc[ot][pt] = (f32x4){0.f,0.f,0.f,0.f};
    #pragma unroll
    for (int ks = 0; ks < 4; ++ks)
        #pragma unroll
        for (int pt = 0; pt < 4; ++pt) {
            short8 bfr = *(const short8*)&fb[(pB + pt*16 + lm)*128 + ((ks*32 + 8*lg) ^ swzl)];
            facc[0][pt] = __builtin_amdgcn_mfma_f32_16x16x32_bf16(af2[0][ks], bfr, facc[0][pt], 0,0,0);
            facc[1][pt] = __builtin_amdgcn_mfma_f32_16x16x32_bf16(af2[1][ks], bfr, facc[1][pt], 0,0,0);
        }
    // fold b2 into facc (single source of truth for staging & Gram)
    #pragma unroll
    for (int ot = 0; ot < 2; ++ot) {
        float b2r0 = b2v[o0 + ot*16 + 4*lg + 0], b2r1 = b2v[o0 + ot*16 + 4*lg + 1];
        float b2r2 = b2v[o0 + ot*16 + 4*lg + 2], b2r3 = b2v[o0 + ot*16 + 4*lg + 3];
        #pragma unroll
        for (int pt = 0; pt < 4; ++pt) {
            facc[ot][pt][0] += b2r0; facc[ot][pt][1] += b2r1;
            facc[ot][pt][2] += b2r2; facc[ot][pt][3] += b2r3;
        }
    }
    __syncthreads();   // all g reads done before f^T overwrites fb

    // ---- f^T (bf16) into fb for Gram; half-0 waves also stage fp32
    #pragma unroll
    for (int ot = 0; ot < 2; ++ot)
        #pragma unroll
        for (int pt = 0; pt < 4; ++pt) {
            f32x4 f = facc[ot][pt];
            int p = pt*16 + lm;                    // window-local 0..63
            uint2 pk; pk.x = pack2(f[0], f[1]); pk.y = pack2(f[2], f[3]);
            *(uint2*)&fb[(pB + p)*128 + ((o0 + ot*16 + 4*lg) ^ swzl)] = pk;
        }
    if (half == 0) {
        #pragma unroll
        for (int ot = 0; ot < 2; ++ot)
            #pragma unroll
            for (int pt = 0; pt < 4; ++pt) {
                int p = pt*16 + lm, py = p >> 3, px = p & 7;
                int col = py*16 + win*8 + px;
                int cb = (ow & 1)*32 + ot*16 + 4*lg;
                f32x4 f = facc[ot][pt];
                st[(cb+0)*136 + col] = f[0];
                st[(cb+1)*136 + col] = f[1];
                st[(cb+2)*136 + col] = f[2];
                st[(cb+3)*136 + col] = f[3];
            }
    }
    __syncthreads();

    // ---- stream half 0 out (NT float4, 64B row segments), then Gram
    {
        #pragma unroll
        for (int i = 0; i < 4; ++i) {
            int f4 = t + i*512;
            int cl = f4 >> 5, rem = f4 & 31;
            int y = rem >> 2, xq2 = rem & 3;
            f32x4 val = *(const f32x4*)&st[cl*136 + y*16 + xq2*4];
            __builtin_nontemporal_store(val,
                (f32x4*)(out + (size_t)n*CH*HW + (size_t)cl*HW
                             + (size_t)(h0 + y)*IMGW + w0c + xq2*4));
        }
    }
    const float invT = 1.f / temp[0];
    f32x4 sacc[4];
    #pragma unroll
    for (int qt = 0; qt < 4; ++qt) sacc[qt] = (f32x4){0.f,0.f,0.f,0.f};
    #pragma unroll
    for (int ks = 0; ks < 4; ++ks) {
        short8 afr = *(const short8*)&fb[(pB + 16*ow + lm)*128 + ((ks*32 + 8*lg) ^ swzl)];
        #pragma unroll
        for (int qt = 0; qt < 4; ++qt) {
            short8 bfr = *(const short8*)&fb[(pB + qt*16 + lm)*128 + ((ks*32 + 8*lg) ^ swzl)];
            sacc[qt] = __builtin_amdgcn_mfma_f32_16x16x32_bf16(afr, bfr, sacc[qt], 0,0,0);
        }
    }
    __syncthreads();   // half-0 staging reads done

    // ---- stage + stream half 1
    if (half == 1) {
        #pragma unroll
        for (int ot = 0; ot < 2; ++ot)
            #pragma unroll
            for (int pt = 0; pt < 4; ++pt) {
                int p = pt*16 + lm, py = p >> 3, px = p & 7;
                int col = py*16 + win*8 + px;
                int cb = (ow & 1)*32 + ot*16 + 4*lg;
                f32x4 f = facc[ot][pt];
                st[(cb+0)*136 + col] = f[0];
                st[(cb+1)*136 + col] = f[1];
                st[(cb+2)*136 + col] = f[2];
                st[(cb+3)*136 + col] = f[3];
            }
    }
    __syncthreads();
    {
        #pragma unroll
        for (int i = 0; i < 4; ++i) {
            int f4 = t + i*512;
            int cl = f4 >> 5, rem = f4 & 31;
            int y = rem >> 2, xq2 = rem & 3;
            f32x4 val = *(const f32x4*)&st[cl*136 + y*16 + xq2*4];
            __builtin_nontemporal_store(val,
                (f32x4*)(out + (size_t)n*CH*HW + (size_t)(64 + cl)*HW
                             + (size_t)(h0 + y)*IMGW + w0c + xq2*4));
        }
    }

    // ---- row LSE + loss partial (registers only)
    float lossAcc = 0.f;
    #pragma unroll
    for (int r = 0; r < 4; ++r) {
        float v0 = sacc[0][r]*invT, v1 = sacc[1][r]*invT;
        float v2 = sacc[2][r]*invT, v3 = sacc[3][r]*invT;
        float m = fmaxf(fmaxf(v0, v1), fmaxf(v2, v3));
        m = fmaxf(m, __shfl_xor(m, 1)); m = fmaxf(m, __shfl_xor(m, 2));
        m = fmaxf(m, __shfl_xor(m, 4)); m = fmaxf(m, __shfl_xor(m, 8));
        float s = __expf(v0-m) + __expf(v1-m) + __expf(v2-m) + __expf(v3-m);
        s += __shfl_xor(s, 1); s += __shfl_xor(s, 2);
        s += __shfl_xor(s, 4); s += __shfl_xor(s, 8);
        float lse = m + logf(s);
        if (lm == 4*lg + r) {
            float dv = (ow == 0) ? v0 : (ow == 1) ? v1 : (ow == 2) ? v2 : v3;
            lossAcc += lse - dv;
        }
    }
    lossAcc += __shfl_xor(lossAcc, 1);  lossAcc += __shfl_xor(lossAcc, 2);
    lossAcc += __shfl_xor(lossAcc, 4);  lossAcc += __shfl_xor(lossAcc, 8);
    lossAcc += __shfl_xor(lossAcc, 16); lossAcc += __shfl_xor(lossAcc, 32);
    if (l == 0) ws[WS_LOSS + (size_t)b*8 + wid] = lossAcc;
}

// ------------------------------------------ K4: deterministic loss reduction
__global__ void k4_loss(const float* __restrict__ ws, float* __restrict__ out) {
    __shared__ float red[4];
    int t = threadIdx.x;
    float s = 0.f;
    for (int i = t; i < 40960; i += 256) s += ws[WS_LOSS + i];
    #pragma unroll
    for (int off = 32; off > 0; off >>= 1) s += __shfl_down(s, off, 64);
    if ((t & 63) == 0) red[t >> 6] = s;
    __syncthreads();
    if (t == 0) out[FEATS_ELEMS] = (red[0] + red[1] + red[2] + red[3]) * (1.f/655360.f);
}

// ---------------------------------------------------------------- launcher
extern "C" void kernel_launch(void* const* d_in, const int* in_sizes, int n_in,
                              void* d_out, int out_size, void* d_ws, size_t ws_size,
                              hipStream_t stream) {
    (void)in_sizes; (void)n_in; (void)out_size; (void)ws_size;
    const float* x    = (const float*)d_in[0];
    const float* W1   = (const float*)d_in[1];
    const float* b1   = (const float*)d_in[2];
    const float* gnw  = (const float*)d_in[3];
    const float* gnb  = (const float*)d_in[4];
    const float* W2   = (const float*)d_in[5];
    const float* b2   = (const float*)d_in[6];
    const float* temp = (const float*)d_in[7];
    float* out = (float*)d_out;
    float* ws  = (float*)d_ws;

    hipLaunchKernelGGL(k0_init,    dim3(64),   dim3(256), 0, stream, W1, W2, ws);
    hipLaunchKernelGGL(k1_quad,    dim3(2560), dim3(512), 0, stream, x, ws, b1);
    hipLaunchKernelGGL(k2_final,   dim3(10),   dim3(256), 0, stream, gnw, gnb, ws);
    hipLaunchKernelGGL(k3_consume, dim3(5120), dim3(512), 0, stream, ws, b2, temp, out);
    hipLaunchKernelGGL(k4_loss,    dim3(1),    dim3(256), 0, stream, ws, out);
}

// Round 17
// 274.070 us; speedup vs baseline: 1.0145x; 1.0145x over previous
//
#include <hip/hip_runtime.h>
#include <hip/hip_bf16.h>
#include <math.h>

#define CH 128
#define IMGW 256
#define NIMG 10
#define HW 65536
#define FEATS_ELEMS ((size_t)NIMG*CH*HW)

typedef __attribute__((ext_vector_type(8))) short short8;
typedef __attribute__((ext_vector_type(4))) float f32x4;

// workspace layout (float offsets) — R8 layout
#define WS_W1BF 0          // W1 bf16 [128 o][128 c]
#define WS_W2BF 8192
#define WS_PART 16384      // [5120 logical strips][16] stat partials
#define WS_A    98304      // [10][128] rsig*gn_w
#define WS_CC   99584      // [10][128] affine constant
#define WS_LOSS 100864     // [5120*8] per-(strip,wave) loss partials
#define WS_HT   141824     // h cache: 5120 strips * 8192 floats (16384 bf16)

static __device__ __forceinline__ ushort f2bf(float f) {
    __hip_bfloat16 h = __float2bfloat16(f);
    return *reinterpret_cast<ushort*>(&h);
}
static __device__ __forceinline__ uint pack2(float a, float b) {
    return (uint)f2bf(a) | ((uint)f2bf(b) << 16);
}
static __device__ __forceinline__ float gelu_fast(float v) {
    float v2 = v*v;
    float z2 = v * fmaf(0.07135481627f, v2, 1.59576912161f);
    return v / (1.0f + __expf(-z2));
}
// 4x4 cross-lane transpose among lanes differing in masks m1 (role bit1)
// and m0 (role bit0); a = role index 0..3.
static __device__ __forceinline__ void xpose4m(int a, int m1, int m0,
        float& r0, float& r1, float& r2, float& r3) {
    float s0v = (a&2) ? r0 : r2, s1v = (a&2) ? r1 : r3;
    float u0 = __shfl_xor(s0v, m1), u1 = __shfl_xor(s1v, m1);
    if (a&2) { r0 = u0; r1 = u1; } else { r2 = u0; r3 = u1; }
    float sA = (a&1) ? r0 : r1; float uA = __shfl_xor(sA, m0);
    if (a&1) r0 = uA; else r1 = uA;
    float sB = (a&1) ? r2 : r3; float uB = __shfl_xor(sB, m0);
    if (a&1) r2 = uB; else r3 = uB;
}

// ------------------------------------------------ K0: W->bf16
__global__ void k0_init(const float* __restrict__ W1, const float* __restrict__ W2,
                        float* __restrict__ ws) {
    int idx = blockIdx.x*256 + threadIdx.x;     // 0..16383
    uint* w1b = (uint*)(ws + WS_W1BF);
    uint* w2b = (uint*)(ws + WS_W2BF);
    if (idx < 8192) {
        w1b[idx] = pack2(W1[2*idx], W1[2*idx+1]);
    } else {
        int j = idx - 8192;
        w2b[j] = pack2(W2[2*j], W2[2*j+1]);
    }
}

// K1: QUAD-STRIP (8 rows x 32 cols = 4 windows = 2 h-strips), 512 thr.
// Full 128B-line NT wave-loads. Strip A is streamed to the h-cache RIGHT
// AFTER phase-0's h^T completes, so its 64KB of stores drain under phase-1
// compute instead of serializing at the block tail.
__global__ __launch_bounds__(512, 4) void k1_quad(const float* __restrict__ x,
        float* ws, const float* __restrict__ b1v) {
    __shared__ __align__(16) ushort xq[256*128];   // x^T then h^T (64 KB)
    __shared__ float sp[32];
    const int t = threadIdx.x, b = blockIdx.x;
    const int qidx = (b & 7)*320 + (b >> 3);       // bijective, 2560%8==0
    const int n = qidx >> 8, rem = qidx & 255;
    const int sr = rem >> 3, qc = rem & 7;
    const int h0 = sr*8, w0q = qc*32;
    const size_t g0 = (size_t)n*512 + sr*16 + 2*qc;   // logical strip ids
    const int l = t & 63, wid = t >> 6;
    const int lm = l & 15, lg = l >> 4;
    const int swzl = 8*(lm&7);
    const ushort* w1b = (const ushort*)(ws + WS_W1BF);
    const int ow = wid & 3, o0 = 32*ow;

    // ---- staging: 16 NT wave-loads, each = 8 full 128B lines
    const int oct = l >> 3, j = l & 7;
    f32x4 v[16];
    {
        const float* xb = x + (size_t)n*CH*HW + (size_t)h0*IMGW + w0q;
        #pragma unroll
        for (int i = 0; i < 16; ++i) {
            int c = (i & 1)*64 + 8*wid + oct;
            int dy = i >> 1;
            v[i] = __builtin_nontemporal_load(
                       (const f32x4*)(xb + (size_t)c*HW + dy*IMGW + 4*j));
        }
    }
    __builtin_amdgcn_sched_barrier(0);

    short8 af[2][4];
    #pragma unroll
    for (int ot = 0; ot < 2; ++ot)
        #pragma unroll
        for (int ks = 0; ks < 4; ++ks)
            af[ot][ks] = *(const short8*)(w1b + (size_t)(o0 + ot*16 + lm)*128 + ks*32 + 8*lg);
    float bv[2][4];
    #pragma unroll
    for (int ot = 0; ot < 2; ++ot)
        #pragma unroll
        for (int r = 0; r < 4; ++r) bv[ot][r] = b1v[o0 + ot*16 + 4*lg + r];

    // ---- transpose (4x4 across lane-xor 16/8) + pack -> xq[P][c^swz]
    {
        const int a = oct & 3, A = oct >> 2;
        #pragma unroll
        for (int i = 0; i < 16; ++i) {
            float r0 = v[i][0], r1 = v[i][1], r2 = v[i][2], r3 = v[i][3];
            xpose4m(a, 16, 8, r0, r1, r2, r3);
            int col = 4*j + a;                       // 0..31 within quad
            int P = (col >> 3)*64 + (i >> 1)*8 + (col & 7);
            int cq = (i & 1)*64 + 8*wid + 4*A;
            uint2 pk; pk.x = pack2(r0, r1); pk.y = pack2(r2, r3);
            *(uint2*)&xq[P*128 + (cq ^ (8*(P&7)))] = pk;
        }
    }
    __syncthreads();

    float s1[2] = {0.f, 0.f}, s2[2] = {0.f, 0.f};

    // ---- phase 0: conv wins 0|1 (rows 0..127)
    {
        const int win = wid >> 2;
        f32x4 hacc[2][4];
        #pragma unroll
        for (int ot = 0; ot < 2; ++ot)
            #pragma unroll
            for (int pt = 0; pt < 4; ++pt)
                hacc[ot][pt] = (f32x4){bv[ot][0], bv[ot][1], bv[ot][2], bv[ot][3]};
        #pragma unroll
        for (int ks = 0; ks < 4; ++ks)
            #pragma unroll
            for (int pt = 0; pt < 4; ++pt) {
                short8 bfr = *(const short8*)&xq[(win*64 + pt*16 + lm)*128 + ((ks*32 + 8*lg) ^ swzl)];
                hacc[0][pt] = __builtin_amdgcn_mfma_f32_16x16x32_bf16(af[0][ks], bfr, hacc[0][pt], 0,0,0);
                hacc[1][pt] = __builtin_amdgcn_mfma_f32_16x16x32_bf16(af[1][ks], bfr, hacc[1][pt], 0,0,0);
            }
        #pragma unroll
        for (int ot = 0; ot < 2; ++ot)
            #pragma unroll
            for (int pt = 0; pt < 4; ++pt)
                #pragma unroll
                for (int r = 0; r < 4; ++r) {
                    float h = hacc[ot][pt][r];
                    s1[ot] += h; s2[ot] += h*h;
                }
        __syncthreads();   // all phase-0 conv reads complete
        #pragma unroll
        for (int ot = 0; ot < 2; ++ot)
            #pragma unroll
            for (int pt = 0; pt < 4; ++pt) {
                f32x4 h = hacc[ot][pt];
                int P = win*64 + pt*16 + lm;
                uint2 pk; pk.x = pack2(h[0], h[1]); pk.y = pack2(h[2], h[3]);
                *(uint2*)&xq[P*128 + ((o0 + ot*16 + 4*lg) ^ swzl)] = pk;
            }
    }
    __syncthreads();   // strip A (rows 0..127) fully written

    // ---- stream strip g0 NOW: stores drain under phase-1 compute.
    {
        const uint4* srcv = (const uint4*)xq;
        uint4* d0 = (uint4*)(ws + WS_HT + g0*8192);
        #pragma unroll
        for (int i = 0; i < 4; ++i) d0[t + i*512] = srcv[t + i*512];
    }

    // ---- phase 1: conv wins 2|3 (rows 128..255; disjoint from stream reads)
    {
        const int win = 2 + (wid >> 2);
        f32x4 hacc[2][4];
        #pragma unroll
        for (int ot = 0; ot < 2; ++ot)
            #pragma unroll
            for (int pt = 0; pt < 4; ++pt)
                hacc[ot][pt] = (f32x4){bv[ot][0], bv[ot][1], bv[ot][2], bv[ot][3]};
        #pragma unroll
        for (int ks = 0; ks < 4; ++ks)
            #pragma unroll
            for (int pt = 0; pt < 4; ++pt) {
                short8 bfr = *(const short8*)&xq[(win*64 + pt*16 + lm)*128 + ((ks*32 + 8*lg) ^ swzl)];
                hacc[0][pt] = __builtin_amdgcn_mfma_f32_16x16x32_bf16(af[0][ks], bfr, hacc[0][pt], 0,0,0);
                hacc[1][pt] = __builtin_amdgcn_mfma_f32_16x16x32_bf16(af[1][ks], bfr, hacc[1][pt], 0,0,0);
            }
        #pragma unroll
        for (int ot = 0; ot < 2; ++ot)
            #pragma unroll
            for (int pt = 0; pt < 4; ++pt)
                #pragma unroll
                for (int r = 0; r < 4; ++r) {
                    float h = hacc[ot][pt][r];
                    s1[ot] += h; s2[ot] += h*h;
                }
        __syncthreads();   // all phase-1 conv reads complete
        #pragma unroll
        for (int ot = 0; ot < 2; ++ot)
            #pragma unroll
            for (int pt = 0; pt < 4; ++pt) {
                f32x4 h = hacc[ot][pt];
                int P = win*64 + pt*16 + lm;
                uint2 pk; pk.x = pack2(h[0], h[1]); pk.y = pack2(h[2], h[3]);
                *(uint2*)&xq[P*128 + ((o0 + ot*16 + 4*lg) ^ swzl)] = pk;
            }
    }

    // ---- stats: wave-reduce (both phases), stash per wave
    #pragma unroll
    for (int ot = 0; ot < 2; ++ot) {
        float a = s1[ot], qq = s2[ot];
        #pragma unroll
        for (int off = 1; off < 64; off <<= 1) {
            a += __shfl_xor(a, off); qq += __shfl_xor(qq, off);
        }
        if (l == 0) { sp[wid*4 + ot*2] = a; sp[wid*4 + ot*2 + 1] = qq; }
    }
    __syncthreads();   // strip B complete + sp ready

    // ---- stream strip g1 + stat partials
    {
        const uint4* srcv = (const uint4*)xq;
        uint4* d1 = (uint4*)(ws + WS_HT + (g0+1)*8192);
        #pragma unroll
        for (int i = 0; i < 4; ++i) d1[t + i*512] = srcv[2048 + t + i*512];
    }
    if (t < 16) {
        int which = t >> 3, g = t & 7;
        int ow_ = g >> 1, ot_ = g & 1;
        float vv = sp[ow_*4 + ot_*2 + which] + sp[(4+ow_)*4 + ot_*2 + which];
        ws[WS_PART + g0*16 + t] = vv;
        ws[WS_PART + (g0+1)*16 + t] = 0.0f;
    }
}

// K2: parallel reduce of strip partials (grid 10 = one block per image)
__global__ __launch_bounds__(256) void k2_final(const float* __restrict__ gnw,
        const float* __restrict__ gnb, float* ws) {
    __shared__ float red[256];
    __shared__ float tot[16];
    __shared__ float muS[8], rsS[8];
    const int t = threadIdx.x, n = blockIdx.x;
    const int s = t & 15, i0 = t >> 4;
    const float* base = ws + WS_PART + (size_t)n*512*16;
    float p = 0.f;
    for (int k = 0; k < 32; ++k) p += base[(i0 + 16*k)*16 + s];
    red[t] = p;
    __syncthreads();
    if (t < 16) {
        float v = 0.f;
        #pragma unroll
        for (int jj = 0; jj < 16; ++jj) v += red[jj*16 + t];
        tot[t] = v;
    }
    __syncthreads();
    if (t < 8) {
        const float inv = 1.0f/1048576.0f;      // 16 ch * 65536 px
        float mu  = tot[t]*inv;
        float var = tot[8 + t]*inv - mu*mu;
        muS[t] = mu; rsS[t] = rsqrtf(var + 1e-5f);
    }
    __syncthreads();
    if (t < 128) {
        int g = t >> 4;
        float a = rsS[g]*gnw[t];
        ws[WS_A  + n*128 + t] = a;
        ws[WS_CC + n*128 + t] = gnb[t] - muS[g]*a;   // b1 already inside h
    }
}

// K3 (== R8): 2-window strip, h via global_load_lds, GN+GELU in place,
// conv2, LDS-staged 64B NT feats stores, Gram + LSE.
__global__ __launch_bounds__(512, 4) void k3_consume(float* ws,
        const float* __restrict__ b2v, const float* __restrict__ temp,
        float* __restrict__ out) {
    __shared__ __align__(16) ushort fb[128*128];   // h -> g -> f^T bf16 (32 KB)
    __shared__ __align__(16) float  st[64*136];    // fp32 out staging  (34 KB)
    const int t = threadIdx.x, b = blockIdx.x;
    const int swz = (b & 7)*640 + (b >> 3);        // logical strip id
    const int n = swz >> 9, strip = swz & 511;
    const int h0 = (strip >> 4)*8, w0c = (strip & 15)*16;
    const int l = t & 63, wid = t >> 6;
    const int lm = l & 15, lg = l >> 4;
    const int swzl = 8*(lm&7);
    const ushort* w2b = (const ushort*)(ws + WS_W2BF);

    // ---- load h strip: direct global->LDS (verbatim; lane-linear both sides)
    {
        const char* src = (const char*)(ws + WS_HT + (size_t)swz*8192);
        #pragma unroll
        for (int i = 0; i < 4; ++i) {
            __builtin_amdgcn_global_load_lds(
                (const __attribute__((address_space(1))) void*)(src + ((size_t)(t + i*512))*16),
                (__attribute__((address_space(3))) void*)&fb[(size_t)(t + i*512)*8],
                16, 0, 0);
        }
    }
    __syncthreads();

    // ---- GN affine + GELU, in place (4096 uint2 / 512 thr)
    {
        uint2* hu = (uint2*)fb;
        const float* aP = ws + WS_A  + n*128;
        const float* cP = ws + WS_CC + n*128;
        #pragma unroll
        for (int i = 0; i < 8; ++i) {
            int c0 = t + i*512;
            int p = c0 >> 5;
            int o = ((c0 & 31)*4) ^ (8*(p&7));
            uint2 v = hu[c0];
            float hv0 = __uint_as_float((v.x & 0xffffu) << 16);
            float hv1 = __uint_as_float(v.x & 0xffff0000u);
            float hv2 = __uint_as_float((v.y & 0xffffu) << 16);
            float hv3 = __uint_as_float(v.y & 0xffff0000u);
            float g0 = gelu_fast(fmaf(hv0, aP[o],   cP[o]));
            float g1 = gelu_fast(fmaf(hv1, aP[o+1], cP[o+1]));
            float g2 = gelu_fast(fmaf(hv2, aP[o+2], cP[o+2]));
            float g3 = gelu_fast(fmaf(hv3, aP[o+3], cP[o+3]));
            uint2 pk; pk.x = pack2(g0, g1); pk.y = pack2(g2, g3);
            hu[c0] = pk;
        }
    }
    __syncthreads();

    const int win = wid >> 2, ow = wid & 3;
    const int o0 = 32*ow, pB = win*64;
    const int half = ow >> 1;                      // channel-half of this wave

    // ---- conv2
    short8 af2[2][4];
    #pragma unroll
    for (int ot = 0; ot < 2; ++ot)
        #pragma unroll
        for (int ks = 0; ks < 4; ++ks)
            af2[ot][ks] = *(const short8*)(w2b + (size_t)(o0 + ot*16 + lm)*128 + ks*32 + 8*lg);
    f32x4 facc[2][4];
    #pragma unroll
    for (int ot = 0; ot < 2; ++ot)
        #pragma unroll
        for (int pt = 0; pt < 4; ++pt) facc[ot][pt] = (f32x4){0.f,0.f,0.f,0.f};
    #pragma unroll
    for (int ks = 0; ks < 4; ++ks)
        #pragma unroll
        for (int pt = 0; pt < 4; ++pt) {
            short8 bfr = *(const short8*)&fb[(pB + pt*16 + lm)*128 + ((ks*32 + 8*lg) ^ swzl)];
            facc[0][pt] = __builtin_amdgcn_mfma_f32_16x16x32_bf16(af2[0][ks], bfr, facc[0][pt], 0,0,0);
            facc[1][pt] = __builtin_amdgcn_mfma_f32_16x16x32_bf16(af2[1][ks], bfr, facc[1][pt], 0,0,0);
        }
    // fold b2 into facc (single source of truth for staging & Gram)
    #pragma unroll
    for (int ot = 0; ot < 2; ++ot) {
        float b2r0 = b2v[o0 + ot*16 + 4*lg + 0], b2r1 = b2v[o0 + ot*16 + 4*lg + 1];
        float b2r2 = b2v[o0 + ot*16 + 4*lg + 2], b2r3 = b2v[o0 + ot*16 + 4*lg + 3];
        #pragma unroll
        for (int pt = 0; pt < 4; ++pt) {
            facc[ot][pt][0] += b2r0; facc[ot][pt][1] += b2r1;
            facc[ot][pt][2] += b2r2; facc[ot][pt][3] += b2r3;
        }
    }
    __syncthreads();   // all g reads done before f^T overwrites fb

    // ---- f^T (bf16) into fb for Gram; half-0 waves also stage fp32
    #pragma unroll
    for (int ot = 0; ot < 2; ++ot)
        #pragma unroll
        for (int pt = 0; pt < 4; ++pt) {
            f32x4 f = facc[ot][pt];
            int p = pt*16 + lm;                    // window-local 0..63
            uint2 pk; pk.x = pack2(f[0], f[1]); pk.y = pack2(f[2], f[3]);
            *(uint2*)&fb[(pB + p)*128 + ((o0 + ot*16 + 4*lg) ^ swzl)] = pk;
        }
    if (half == 0) {
        #pragma unroll
        for (int ot = 0; ot < 2; ++ot)
            #pragma unroll
            for (int pt = 0; pt < 4; ++pt) {
                int p = pt*16 + lm, py = p >> 3, px = p & 7;
                int col = py*16 + win*8 + px;
                int cb = (ow & 1)*32 + ot*16 + 4*lg;
                f32x4 f = facc[ot][pt];
                st[(cb+0)*136 + col] = f[0];
                st[(cb+1)*136 + col] = f[1];
                st[(cb+2)*136 + col] = f[2];
                st[(cb+3)*136 + col] = f[3];
            }
    }
    __syncthreads();

    // ---- stream half 0 out (NT float4, 64B row segments), then Gram
    {
        #pragma unroll
        for (int i = 0; i < 4; ++i) {
            int f4 = t + i*512;
            int cl = f4 >> 5, rem = f4 & 31;
            int y = rem >> 2, xq2 = rem & 3;
            f32x4 val = *(const f32x4*)&st[cl*136 + y*16 + xq2*4];
            __builtin_nontemporal_store(val,
                (f32x4*)(out + (size_t)n*CH*HW + (size_t)cl*HW
                             + (size_t)(h0 + y)*IMGW + w0c + xq2*4));
        }
    }
    const float invT = 1.f / temp[0];
    f32x4 sacc[4];
    #pragma unroll
    for (int qt = 0; qt < 4; ++qt) sacc[qt] = (f32x4){0.f,0.f,0.f,0.f};
    #pragma unroll
    for (int ks = 0; ks < 4; ++ks) {
        short8 afr = *(const short8*)&fb[(pB + 16*ow + lm)*128 + ((ks*32 + 8*lg) ^ swzl)];
        #pragma unroll
        for (int qt = 0; qt < 4; ++qt) {
            short8 bfr = *(const short8*)&fb[(pB + qt*16 + lm)*128 + ((ks*32 + 8*lg) ^ swzl)];
            sacc[qt] = __builtin_amdgcn_mfma_f32_16x16x32_bf16(afr, bfr, sacc[qt], 0,0,0);
        }
    }
    __syncthreads();   // half-0 staging reads done

    // ---- stage + stream half 1
    if (half == 1) {
        #pragma unroll
        for (int ot = 0; ot < 2; ++ot)
            #pragma unroll
            for (int pt = 0; pt < 4; ++pt) {
                int p = pt*16 + lm, py = p >> 3, px = p & 7;
                int col = py*16 + win*8 + px;
                int cb = (ow & 1)*32 + ot*16 + 4*lg;
                f32x4 f = facc[ot][pt];
                st[(cb+0)*136 + col] = f[0];
                st[(cb+1)*136 + col] = f[1];
                st[(cb+2)*136 + col] = f[2];
                st[(cb+3)*136 + col] = f[3];
            }
    }
    __syncthreads();
    {
        #pragma unroll
        for (int i = 0; i < 4; ++i) {
            int f4 = t + i*512;
            int cl = f4 >> 5, rem = f4 & 31;
            int y = rem >> 2, xq2 = rem & 3;
            f32x4 val = *(const f32x4*)&st[cl*136 + y*16 + xq2*4];
            __builtin_nontemporal_store(val,
                (f32x4*)(out + (size_t)n*CH*HW + (size_t)(64 + cl)*HW
                             + (size_t)(h0 + y)*IMGW + w0c + xq2*4));
        }
    }

    // ---- row LSE + loss partial (registers only)
    float lossAcc = 0.f;
    #pragma unroll
    for (int r = 0; r < 4; ++r) {
        float v0 = sacc[0][r]*invT, v1 = sacc[1][r]*invT;
        float v2 = sacc[2][r]*invT, v3 = sacc[3][r]*invT;
        float m = fmaxf(fmaxf(v0, v1), fmaxf(v2, v3));
        m = fmaxf(m, __shfl_xor(m, 1)); m = fmaxf(m, __shfl_xor(m, 2));
        m = fmaxf(m, __shfl_xor(m, 4)); m = fmaxf(m, __shfl_xor(m, 8));
        float s = __expf(v0-m) + __expf(v1-m) + __expf(v2-m) + __expf(v3-m);
        s += __shfl_xor(s, 1); s += __shfl_xor(s, 2);
        s += __shfl_xor(s, 4); s += __shfl_xor(s, 8);
        float lse = m + logf(s);
        if (lm == 4*lg + r) {
            float dv = (ow == 0) ? v0 : (ow == 1) ? v1 : (ow == 2) ? v2 : v3;
            lossAcc += lse - dv;
        }
    }
    lossAcc += __shfl_xor(lossAcc, 1);  lossAcc += __shfl_xor(lossAcc, 2);
    lossAcc += __shfl_xor(lossAcc, 4);  lossAcc += __shfl_xor(lossAcc, 8);
    lossAcc += __shfl_xor(lossAcc, 16); lossAcc += __shfl_xor(lossAcc, 32);
    if (l == 0) ws[WS_LOSS + (size_t)b*8 + wid] = lossAcc;
}

// ------------------------------------------ K4: deterministic loss reduction
__global__ void k4_loss(const float* __restrict__ ws, float* __restrict__ out) {
    __shared__ float red[4];
    int t = threadIdx.x;
    float s = 0.f;
    for (int i = t; i < 40960; i += 256) s += ws[WS_LOSS + i];
    #pragma unroll
    for (int off = 32; off > 0; off >>= 1) s += __shfl_down(s, off, 64);
    if ((t & 63) == 0) red[t >> 6] = s;
    __syncthreads();
    if (t == 0) out[FEATS_ELEMS] = (red[0] + red[1] + red[2] + red[3]) * (1.f/655360.f);
}

// ---------------------------------------------------------------- launcher
extern "C" void kernel_launch(void* const* d_in, const int* in_sizes, int n_in,
                              void* d_out, int out_size, void* d_ws, size_t ws_size,
                              hipStream_t stream) {
    (void)in_sizes; (void)n_in; (void)out_size; (void)ws_size;
    const float* x    = (const float*)d_in[0];
    const float* W1   = (const float*)d_in[1];
    const float* b1   = (const float*)d_in[2];
    const float* gnw  = (const float*)d_in[3];
    const float* gnb  = (const float*)d_in[4];
    const float* W2   = (const float*)d_in[5];
    const float* b2   = (const float*)d_in[6];
    const float* temp = (const float*)d_in[7];
    float* out = (float*)d_out;
    float* ws  = (float*)d_ws;

    hipLaunchKernelGGL(k0_init,    dim3(64),   dim3(256), 0, stream, W1, W2, ws);
    hipLaunchKernelGGL(k1_quad,    dim3(2560), dim3(512), 0, stream, x, ws, b1);
    hipLaunchKernelGGL(k2_final,   dim3(10),   dim3(256), 0, stream, gnw, gnb, ws);
    hipLaunchKernelGGL(k3_consume, dim3(5120), dim3(512), 0, stream, ws, b2, temp, out);
    hipLaunchKernelGGL(k4_loss,    dim3(1),    dim3(256), 0, stream, ws, out);
}